// Round 5
// baseline (5327.603 us; speedup 1.0000x reference)
//
#include <hip/hip_runtime.h>
#include <math.h>
#include <type_traits>

// Problem constants
#define NB 512     // batch
#define HD 512     // hidden
#define CD 64      // in channels
#define TD 168     // encode length
#define DSTEPS 24  // decoder steps
#define OUTC 64    // out channels
#define GATES 2048 // 4*HD
#define KWE (HD + CD)   // encoder K = 576
#define NCHE 18         // encoder K chunks (32 each)
#define NCHD 16         // decoder K chunks

typedef __attribute__((ext_vector_type(8))) short bf16x8;
typedef __attribute__((ext_vector_type(4))) float f32x4;

__device__ __forceinline__ float sigmf(float x) { return 1.0f / (1.0f + expf(-x)); }
__device__ __forceinline__ float bf2f(unsigned short h) {
    return __uint_as_float(((unsigned)h) << 16);
}
__device__ __forceinline__ unsigned short f2bf(float x) {  // round-to-nearest-even
    unsigned u = __float_as_uint(x);
    return (unsigned short)((u + 0x7fffu + ((u >> 16) & 1u)) >> 16);
}
__device__ __forceinline__ unsigned packsplit(float v) {   // bf16 hi|lo packed
    unsigned short hi = f2bf(v);
    unsigned short lo = f2bf(v - bf2f(hi));
    return ((unsigned)hi << 16) | (unsigned)lo;
}

// ---------------------------------------------------------------------------
// Weight prep: split f32 into bf16 hi/lo planes, permuted + fragment-ready.
// Elem [(ch*4+ks)*64 + gc][m] holds source row gate*HD + jt*16 + jj at
// k = ch*32 + ks*8 + m, with gate=(gc>>3)&3, jj=(gc&7)+8*(gc>>5).
// ---------------------------------------------------------------------------
__global__ __launch_bounds__(256)
void prep_wfrag(const float* __restrict__ Whh, const float* __restrict__ Wih,
                unsigned short* __restrict__ Ph, unsigned short* __restrict__ Pl,
                int nch)
{
    const int jt = blockIdx.x, ch = blockIdx.y;
    const int ks = threadIdx.x >> 6, gc = threadIdx.x & 63;
    const int gate = (gc >> 3) & 3;
    const int jj = (gc & 7) + ((gc >> 5) << 3);
    const int srow = gate * HD + jt * 16 + jj;
    const int k0 = ch * 32 + ks * 8;
    const size_t o = (size_t)jt * (64 * nch * 32) + (size_t)((ch * 4 + ks) * 64 + gc) * 8;
    #pragma unroll
    for (int m = 0; m < 8; ++m) {
        int k = k0 + m;
        float v = (k < HD) ? Whh[(size_t)srow * HD + k] : Wih[(size_t)srow * CD + (k - HD)];
        unsigned short hi = f2bf(v);
        Ph[o + m] = hi;
        Pl[o + m] = f2bf(v - bf2f(hi));
    }
}

// ---------------------------------------------------------------------------
// x prep: (N,C,T) f32 -> packed hi|lo u32 planes xP[t][n][c].
// ---------------------------------------------------------------------------
__global__ __launch_bounds__(256)
void prep_xPk(const float* __restrict__ x, unsigned* __restrict__ Xp)
{
    __shared__ float tile[CD * TD];
    const int n = blockIdx.x;
    for (int e = threadIdx.x; e < CD * TD; e += 256)
        tile[e] = x[(size_t)n * CD * TD + e];
    __syncthreads();
    for (int e = threadIdx.x; e < CD * TD; e += 256) {
        int t = e >> 6, c = e & 63;
        Xp[((size_t)t * NB + n) * CD + c] = packsplit(tile[c * TD + t]);
    }
}

// ---------------------------------------------------------------------------
// Persistent encoder+decoder. 256 blocks x 512 threads (8 waves), 1 block/CU.
// Block (jt = bid>>3, ng = bid&7): tile 64n x 64gc. Full B slab (18 chunks)
// LDS-resident. Wave pairs (w, w^1) split K-chunks by parity: each wave does
// its chunks with a depth-4 register prefetch of its OWN A fragments straight
// from global (no A-LDS, no K-loop barriers). Partial accs reduced via 8KB
// LDS once per step. c in registers; h exchanged as packed u32 via relaxed
// agent atomics; per-step counter barrier + acquire fence.
// ---------------------------------------------------------------------------
__global__ __launch_bounds__(512, 2)
void lstm_persist(const unsigned short* __restrict__ WeH, const unsigned short* __restrict__ WeL,
                  const unsigned short* __restrict__ WdH, const unsigned short* __restrict__ WdL,
                  const unsigned* __restrict__ xP,
                  const float* __restrict__ b_e, const float* __restrict__ b_d,
                  unsigned* __restrict__ hp,   // [2][NB*HD] packed
                  unsigned* __restrict__ hs,   // [DSTEPS][NB*HD] packed
                  unsigned* __restrict__ cnt)
{
    __shared__ unsigned short Bh[NCHE * 2048];   // 73728 B
    __shared__ unsigned short Bl[NCHE * 2048];   // 73728 B
    __shared__ float red[2048];                  // 8192 B acc-reduction buffer

    const int tid  = threadIdx.x;
    const int lane = tid & 63;
    const int w    = tid >> 6;           // 0..7
    const int wk   = w & 1;              // K-parity
    const int wp   = w >> 1;             // wave-pair id 0..3
    const int wn   = wp & 1, wg = wp >> 1;
    const int jt   = blockIdx.x >> 3;    // 0..31
    const int ng   = blockIdx.x & 7;     // group == XCD (heuristic affinity)
    const int n0   = ng * 64;

    const int rs    = lane >> 4;         // frag k-slot 0..3
    const int ks8   = rs * 8;            // elem offset within chunk
    const int arow0 = n0 + wn * 32 + (lane & 15);
    const int p     = (lane >> 3) & 1;
    const int j     = jt * 16 + (lane & 7) + (wg << 3);

    const size_t slabE = (size_t)jt * (64 * KWE);
    const size_t slabD = (size_t)jt * (64 * HD);
    const size_t NH    = (size_t)NB * HD;

    // One-time encoder B stage (all 18 chunks) into LDS.
    for (int e = tid; e < NCHE * 256; e += 512) {
        *(bf16x8*)&Bh[(size_t)e * 8] = *(const bf16x8*)&WeH[slabE + (size_t)e * 8];
        *(bf16x8*)&Bl[(size_t)e * 8] = *(const bf16x8*)&WeL[slabE + (size_t)e * 8];
    }
    __syncthreads();

    const float be0 = b_e[0 * HD + j], be1 = b_e[1 * HD + j];
    const float be2 = b_e[2 * HD + j], be3 = b_e[3 * HD + j];
    const float bd0 = b_d[0 * HD + j], bd1 = b_d[1 * HD + j];
    const float bd2 = b_d[2 * HD + j], bd3 = b_d[3 * HD + j];

    float cr[2][4] = {};
    unsigned tgt = 32;
    unsigned* myc = &cnt[ng * 32];

    auto unp = [](const uint4& q0, const uint4& q1, bf16x8& hi, bf16x8& lo) {
        hi[0]=(short)(q0.x>>16); lo[0]=(short)(q0.x&0xffffu);
        hi[1]=(short)(q0.y>>16); lo[1]=(short)(q0.y&0xffffu);
        hi[2]=(short)(q0.z>>16); lo[2]=(short)(q0.z&0xffffu);
        hi[3]=(short)(q0.w>>16); lo[3]=(short)(q0.w&0xffffu);
        hi[4]=(short)(q1.x>>16); lo[4]=(short)(q1.x&0xffffu);
        hi[5]=(short)(q1.y>>16); lo[5]=(short)(q1.y&0xffffu);
        hi[6]=(short)(q1.z>>16); lo[6]=(short)(q1.z&0xffffu);
        hi[7]=(short)(q1.w>>16); lo[7]=(short)(q1.w&0xffffu);
    };

    auto step = [&](auto NIC, auto ENCC, const unsigned* __restrict__ hsrc,
                    const unsigned* __restrict__ xsrc,
                    float b0, float b1, float b2, float b3,
                    unsigned* __restrict__ hdst)
    {
        constexpr int NI   = decltype(NIC)::value;   // chunks per wave
        constexpr bool ENC = decltype(ENCC)::value;
        f32x4 acc[2][2] = {};
        uint4 pf[4][2][2];                           // [slot][fm][quad]

        auto aptr = [&](int i, int fm) -> const uint4* {
            const int ch = wk + 2 * i;
            if (ENC && ch >= NCHD)
                return (const uint4*)(xsrc + (size_t)(arow0 + fm * 16) * CD + (ch - NCHD) * 32 + ks8);
            return (const uint4*)(hsrc + (size_t)(arow0 + fm * 16) * HD + ch * 32 + ks8);
        };

        #pragma unroll
        for (int i = 0; i < 4 && i < NI; ++i) {
            const uint4* p0 = aptr(i, 0);
            const uint4* p1 = aptr(i, 1);
            pf[i][0][0] = p0[0]; pf[i][0][1] = p0[1];
            pf[i][1][0] = p1[0]; pf[i][1][1] = p1[1];
        }

        #pragma unroll
        for (int i = 0; i < NI; ++i) {
            const int sl = i & 3;
            const int ch = wk + 2 * i;
            bf16x8 a_h[2], a_l[2];
            unp(pf[sl][0][0], pf[sl][0][1], a_h[0], a_l[0]);
            unp(pf[sl][1][0], pf[sl][1][1], a_h[1], a_l[1]);
            if (i + 4 < NI) {
                const uint4* p0 = aptr(i + 4, 0);
                const uint4* p1 = aptr(i + 4, 1);
                pf[sl][0][0] = p0[0]; pf[sl][0][1] = p0[1];
                pf[sl][1][0] = p1[0]; pf[sl][1][1] = p1[1];
            }
            bf16x8 b_h[2], b_l[2];
            #pragma unroll
            for (int fg = 0; fg < 2; ++fg) {
                const int bi = ch * 2048 + rs * 512 + (wg * 32 + fg * 16 + (lane & 15)) * 8;
                b_h[fg] = *(const bf16x8*)&Bh[bi];
                b_l[fg] = *(const bf16x8*)&Bl[bi];
            }
            #pragma unroll
            for (int fm = 0; fm < 2; ++fm)
                #pragma unroll
                for (int fg = 0; fg < 2; ++fg) {
                    acc[fm][fg] = __builtin_amdgcn_mfma_f32_16x16x32_bf16(a_h[fm], b_h[fg], acc[fm][fg], 0, 0, 0);
                    acc[fm][fg] = __builtin_amdgcn_mfma_f32_16x16x32_bf16(a_h[fm], b_l[fg], acc[fm][fg], 0, 0, 0);
                    acc[fm][fg] = __builtin_amdgcn_mfma_f32_16x16x32_bf16(a_l[fm], b_h[fg], acc[fm][fg], 0, 0, 0);
                }
        }

        // Cross-parity reduction (2 phases of 8KB), then epilogue on wk==0.
        #pragma unroll
        for (int fm = 0; fm < 2; ++fm) {
            if (wk == 1) {
                *(f32x4*)&red[(wp * 64 + lane) * 8 + 0] = acc[fm][0];
                *(f32x4*)&red[(wp * 64 + lane) * 8 + 4] = acc[fm][1];
            }
            __syncthreads();
            if (wk == 0) {
                acc[fm][0] += *(const f32x4*)&red[(wp * 64 + lane) * 8 + 0];
                acc[fm][1] += *(const f32x4*)&red[(wp * 64 + lane) * 8 + 4];
            }
            __syncthreads();
        }

        if (wk == 0) {
            #pragma unroll
            for (int fm = 0; fm < 2; ++fm)
                #pragma unroll
                for (int r = 0; r < 4; ++r) {
                    float v0 = acc[fm][0][r], v1 = acc[fm][1][r];
                    float u0 = __shfl_xor(v0, 8, 64);
                    float u1 = __shfl_xor(v1, 8, 64);
                    if (p == 0) {
                        int n = n0 + wn * 32 + fm * 16 + ((lane >> 4) << 2) + r;
                        float gi = v0 + b0, gf = u0 + b1, gg = v1 + b2, go = u1 + b3;
                        float cn = sigmf(gf) * cr[fm][r] + sigmf(gi) * tanhf(gg);
                        float hn = sigmf(go) * tanhf(cn);
                        cr[fm][r] = cn;
                        __hip_atomic_store(&hdst[(size_t)n * HD + j], packsplit(hn),
                                           __ATOMIC_RELAXED, __HIP_MEMORY_SCOPE_AGENT);
                    }
                }
        }
    };

    auto ngbar = [&]() {
        __syncthreads();   // drains vmcnt: sc1 h-stores are at coherence point
        if (tid == 0) {
            __hip_atomic_fetch_add(myc, 1u, __ATOMIC_RELAXED, __HIP_MEMORY_SCOPE_AGENT);
            while (__hip_atomic_load(myc, __ATOMIC_RELAXED, __HIP_MEMORY_SCOPE_AGENT) < tgt)
                __builtin_amdgcn_s_sleep(1);
        }
        __syncthreads();
        __builtin_amdgcn_fence(__ATOMIC_ACQUIRE, "agent");  // inv stale cached h
        tgt += 32;
    };

    // ---- encoder: 168 steps (even count -> h_enc lands in slot 0) ----
    for (int t = 0; t < TD; ++t) {
        step(std::integral_constant<int, 9>{}, std::integral_constant<bool, true>{},
             hp + (size_t)(t & 1) * NH, xP + (size_t)t * NB * CD,
             be0, be1, be2, be3,
             hp + (size_t)((t + 1) & 1) * NH);
        ngbar();
    }

    // ---- swap in decoder weights (chunks 0..15 of slab) ----
    for (int e = tid; e < NCHD * 256; e += 512) {
        *(bf16x8*)&Bh[(size_t)e * 8] = *(const bf16x8*)&WdH[slabD + (size_t)e * 8];
        *(bf16x8*)&Bl[(size_t)e * 8] = *(const bf16x8*)&WdL[slabD + (size_t)e * 8];
    }
    __syncthreads();
    #pragma unroll
    for (int fm = 0; fm < 2; ++fm)
        #pragma unroll
        for (int r = 0; r < 4; ++r) cr[fm][r] = 0.f;

    // ---- decoder: 24 steps, outputs land in hs slots ----
    for (int s = 0; s < DSTEPS; ++s) {
        const unsigned* hb = (s == 0) ? hp : hs + (size_t)(s - 1) * NH;
        step(std::integral_constant<int, 8>{}, std::integral_constant<bool, false>{},
             hb, hb, bd0, bd1, bd2, bd3,
             hs + (size_t)s * NH);
        ngbar();
    }
}

// ---------------------------------------------------------------------------
// Dense head: out[n][o][t] = sum_k unpack(hs[t][n][k]) * Wd[t][o][k] + bd.
// ---------------------------------------------------------------------------
__global__ __launch_bounds__(256)
void dense_kernel(const unsigned* __restrict__ hsP,
                  const float* __restrict__ Wd,
                  const float* __restrict__ bd,
                  float* __restrict__ out)
{
    const int t  = blockIdx.y;
    const int n0 = blockIdx.x * 64;
    const int tid = threadIdx.x;
    const int to  = tid & 15;
    const int tn  = tid >> 4;

    __shared__ __align__(16) float aT[32 * 68];
    __shared__ __align__(16) float wT[32 * 68];

    float acc[4][4] = {};

    for (int ch = 0; ch < HD / 32; ++ch) {
        const int k0 = ch * 32;
        __syncthreads();
        #pragma unroll
        for (int i = 0; i < 8; ++i) {
            int e  = tid + i * 256;
            int kk = e & 31;
            int nl = e >> 5;
            unsigned v = hsP[((size_t)t * NB + n0 + nl) * HD + k0 + kk];
            aT[kk * 68 + nl] = bf2f((unsigned short)(v >> 16)) + bf2f((unsigned short)(v & 0xffffu));
            wT[kk * 68 + nl] = Wd[((size_t)t * OUTC + nl) * HD + k0 + kk];
        }
        __syncthreads();
        #pragma unroll
        for (int kk = 0; kk < 32; ++kk) {
            float4 a = *reinterpret_cast<const float4*>(&aT[kk * 68 + tn * 4]);
            float4 w = *reinterpret_cast<const float4*>(&wT[kk * 68 + to * 4]);
            acc[0][0] += a.x * w.x; acc[0][1] += a.x * w.y; acc[0][2] += a.x * w.z; acc[0][3] += a.x * w.w;
            acc[1][0] += a.y * w.x; acc[1][1] += a.y * w.y; acc[1][2] += a.y * w.z; acc[1][3] += a.y * w.w;
            acc[2][0] += a.z * w.x; acc[2][1] += a.z * w.y; acc[2][2] += a.z * w.z; acc[2][3] += a.z * w.w;
            acc[3][0] += a.w * w.x; acc[3][1] += a.w * w.y; acc[3][2] += a.w * w.z; acc[3][3] += a.w * w.w;
        }
    }

    #pragma unroll
    for (int i = 0; i < 4; ++i)
        #pragma unroll
        for (int jq = 0; jq < 4; ++jq) {
            int n = n0 + tn * 4 + i;
            int o = to * 4 + jq;
            out[((size_t)n * OUTC + o) * DSTEPS + t] = acc[i][jq] + bd[t * OUTC + o];
        }
}

// ---------------------------------------------------------------------------
extern "C" void kernel_launch(void* const* d_in, const int* in_sizes, int n_in,
                              void* d_out, int out_size, void* d_ws, size_t ws_size,
                              hipStream_t stream) {
    const float* x       = (const float*)d_in[0];
    const float* W_ih_e  = (const float*)d_in[1];
    const float* W_hh_e  = (const float*)d_in[2];
    const float* b_e     = (const float*)d_in[3];
    const float* W_hh_d  = (const float*)d_in[4];
    const float* b_d     = (const float*)d_in[5];
    const float* W_dense = (const float*)d_in[6];
    const float* b_dense = (const float*)d_in[7];
    float* out = (float*)d_out;

    const size_t NH = (size_t)NB * HD;   // 262144 elems

    char* pws = (char*)d_ws;
    auto alloc = [&](size_t bytes) { char* q = pws; pws += (bytes + 255) & ~(size_t)255; return q; };
    unsigned short* WeH = (unsigned short*)alloc((size_t)GATES * KWE * 2);
    unsigned short* WeL = (unsigned short*)alloc((size_t)GATES * KWE * 2);
    unsigned short* WdH = (unsigned short*)alloc((size_t)GATES * HD * 2);
    unsigned short* WdL = (unsigned short*)alloc((size_t)GATES * HD * 2);
    unsigned*       xPk = (unsigned*)alloc((size_t)TD * NB * CD * 4);
    unsigned*       hp  = (unsigned*)alloc(2 * NH * 4);
    unsigned*       hs  = (unsigned*)alloc((size_t)DSTEPS * NH * 4);
    unsigned*       cnt = (unsigned*)alloc(8 * 32 * sizeof(unsigned));

    // Prep (every call; deterministic)
    prep_wfrag<<<dim3(32, NCHE), dim3(256), 0, stream>>>(W_hh_e, W_ih_e, WeH, WeL, NCHE);
    prep_wfrag<<<dim3(32, NCHD), dim3(256), 0, stream>>>(W_hh_d, W_hh_d, WdH, WdL, NCHD);
    prep_xPk<<<dim3(NB), dim3(256), 0, stream>>>(x, xPk);

    hipMemsetAsync(hp, 0, NH * 4, stream);                 // slot 0 = zeros
    hipMemsetAsync(cnt, 0, 8 * 32 * sizeof(unsigned), stream);

    lstm_persist<<<dim3(256), dim3(512), 0, stream>>>(
        WeH, WeL, WdH, WdL, xPk, b_e, b_d, hp, hs, cnt);

    dense_kernel<<<dim3(NB / 64, DSTEPS), dim3(256), 0, stream>>>(
        hs, W_dense, b_dense, out);
}

// Round 6
// 5011.850 us; speedup vs baseline: 1.0630x; 1.0630x over previous
//
#include <hip/hip_runtime.h>
#include <math.h>
#include <type_traits>

// Problem constants
#define NB 512     // batch
#define HD 512     // hidden
#define CD 64      // in channels
#define TD 168     // encode length
#define DSTEPS 24  // decoder steps
#define OUTC 64    // out channels
#define GATES 2048 // 4*HD
#define KWE (HD + CD)   // encoder K = 576
#define NCHE 18         // encoder K chunks (32 each)
#define NCHD 16         // decoder K chunks
#define NBLDS 15        // B chunks resident in LDS (rest in regs)

typedef __attribute__((ext_vector_type(8))) short bf16x8;
typedef __attribute__((ext_vector_type(4))) float f32x4;

template<int N>  using icn = std::integral_constant<int, N>;
template<bool B> using icb = std::integral_constant<bool, B>;

__device__ __forceinline__ float sigmf(float x) { return 1.0f / (1.0f + expf(-x)); }
__device__ __forceinline__ float bf2f(unsigned short h) {
    return __uint_as_float(((unsigned)h) << 16);
}
__device__ __forceinline__ unsigned short f2bf(float x) {  // round-to-nearest-even
    unsigned u = __float_as_uint(x);
    return (unsigned short)((u + 0x7fffu + ((u >> 16) & 1u)) >> 16);
}
__device__ __forceinline__ unsigned packsplit(float v) {   // bf16 hi|lo packed
    unsigned short hi = f2bf(v);
    unsigned short lo = f2bf(v - bf2f(hi));
    return ((unsigned)hi << 16) | (unsigned)lo;
}

// A-LDS swizzle: plane is [64 rows][32 bf16]; conflict-free for both the
// 16-rows x 4-ks staging writes and the 16-rows x 4-rs b128 frag reads.
// row-bit0 ^= row-bit2 (stays in-plane), ks ^= row&3.
__device__ __forceinline__ int aswz(int r, int ks) {      // byte offset in 4KB
    return ((r * 64) ^ (((r >> 2) & 1) << 6)) + (((ks ^ r) & 3) * 16);
}

// v_perm split of 4 packed (hi<<16|lo) words -> 2 hi-words + 2 lo-words (x2)
__device__ __forceinline__ void split4(uint4 p, uint2& hi, uint2& lo) {
    hi.x = __builtin_amdgcn_perm(p.y, p.x, 0x07060302u);
    hi.y = __builtin_amdgcn_perm(p.w, p.z, 0x07060302u);
    lo.x = __builtin_amdgcn_perm(p.y, p.x, 0x05040100u);
    lo.y = __builtin_amdgcn_perm(p.w, p.z, 0x05040100u);
}

// ---------------------------------------------------------------------------
// Weight prep: split f32 into bf16 hi/lo planes, permuted + fragment-ready.
// Elem [(ch*4+ks)*64 + gc][m] holds source row gate*HD + jt*16 + jj at
// k = ch*32 + ks*8 + m, with gate=(gc>>3)&3, jj=(gc&7)+8*(gc>>5).
// ---------------------------------------------------------------------------
__global__ __launch_bounds__(256)
void prep_wfrag(const float* __restrict__ Whh, const float* __restrict__ Wih,
                unsigned short* __restrict__ Ph, unsigned short* __restrict__ Pl,
                int nch)
{
    const int jt = blockIdx.x, ch = blockIdx.y;
    const int ks = threadIdx.x >> 6, gc = threadIdx.x & 63;
    const int gate = (gc >> 3) & 3;
    const int jj = (gc & 7) + ((gc >> 5) << 3);
    const int srow = gate * HD + jt * 16 + jj;
    const int k0 = ch * 32 + ks * 8;
    const size_t o = (size_t)jt * (64 * nch * 32) + (size_t)((ch * 4 + ks) * 64 + gc) * 8;
    #pragma unroll
    for (int m = 0; m < 8; ++m) {
        int k = k0 + m;
        float v = (k < HD) ? Whh[(size_t)srow * HD + k] : Wih[(size_t)srow * CD + (k - HD)];
        unsigned short hi = f2bf(v);
        Ph[o + m] = hi;
        Pl[o + m] = f2bf(v - bf2f(hi));
    }
}

// ---------------------------------------------------------------------------
// x prep: (N,C,T) f32 -> packed hi|lo u32 planes xP[t][n][c].
// ---------------------------------------------------------------------------
__global__ __launch_bounds__(256)
void prep_xPk(const float* __restrict__ x, unsigned* __restrict__ Xp)
{
    __shared__ float tile[CD * TD];
    const int n = blockIdx.x;
    for (int e = threadIdx.x; e < CD * TD; e += 256)
        tile[e] = x[(size_t)n * CD * TD + e];
    __syncthreads();
    for (int e = threadIdx.x; e < CD * TD; e += 256) {
        int t = e >> 6, c = e & 63;
        Xp[((size_t)t * NB + n) * CD + c] = packsplit(tile[c * TD + t]);
    }
}

// ---------------------------------------------------------------------------
// Persistent encoder+decoder. 256 blocks x 256 threads (4 waves), 1 block/CU.
// Block (jt = bid>>3, ng = bid&7): tile 64n x 64gc.
// Waves specialize by K-chunk (ch%4==w): each wave computes the FULL 4x4 frag
// tile over its chunks; B-LDS read once per chunk; A staged wave-privately
// (no K-loop barriers, loads 2 chunks ahead). Step end: 2-pass LDS reduction
// (fm-ownership), epilogue, packed-u32 h exchange via relaxed agent atomics,
// per-n-group counter barrier + agent acquire fence.
// ---------------------------------------------------------------------------
__global__ __launch_bounds__(256, 1)
void lstm_persist(const unsigned short* __restrict__ WeH, const unsigned short* __restrict__ WeL,
                  const unsigned short* __restrict__ WdH, const unsigned short* __restrict__ WdL,
                  const unsigned* __restrict__ xP,
                  const float* __restrict__ b_e, const float* __restrict__ b_d,
                  unsigned* __restrict__ hp,   // [2][NB*HD] packed
                  unsigned* __restrict__ hs,   // [DSTEPS][NB*HD] packed
                  unsigned* __restrict__ cnt)
{
    __shared__ __align__(16) unsigned short BhS[NBLDS * 2048];  // 61440 B
    __shared__ __align__(16) unsigned short BlS[NBLDS * 2048];  // 61440 B
    __shared__ __align__(16) unsigned short As[4][2][2048];     // 32768 B

    const int tid  = threadIdx.x;
    const int lane = tid & 63;
    const int w    = tid >> 6;          // wave 0..3 (owns chunks ch%4==w, fm=w)
    const int jt   = blockIdx.x >> 3;   // 0..31
    const int ng   = blockIdx.x & 7;    // n-group (== XCD heuristic, perf only)
    const int n0   = ng * 64;

    const int rs    = lane >> 4;        // frag k-slot 0..3
    const int c15   = lane & 15;
    const int p     = (lane >> 3) & 1;
    const int jbase = jt * 16 + (lane & 7);
    const int srow4 = lane >> 2;        // staging sub-row 0..15
    const int sks   = lane & 3;         // staging k-slot 0..3

    const size_t slabE = (size_t)jt * (64 * KWE);
    const size_t slabD = (size_t)jt * (64 * HD);
    const size_t NH    = (size_t)NB * HD;

    // Biases (per-lane, both phases)
    float bje[2][4], bjd[2][4];
    #pragma unroll
    for (int g = 0; g < 4; ++g) {
        bje[0][g] = b_e[g * HD + jbase];
        bje[1][g] = b_e[g * HD + jbase + 8];
        bjd[0][g] = b_d[g * HD + jbase];
        bjd[1][g] = b_d[g * HD + jbase + 8];
    }

    // B-LDS stage (chunks 0..14)
    auto stageB = [&](const unsigned short* PH, const unsigned short* PL, size_t slab) {
        for (int e = tid; e < NBLDS * 256; e += 256) {
            *(bf16x8*)&BhS[(size_t)e * 8] = *(const bf16x8*)&PH[slab + (size_t)e * 8];
            *(bf16x8*)&BlS[(size_t)e * 8] = *(const bf16x8*)&PL[slab + (size_t)e * 8];
        }
    };
    // Tail B chunk (>=15) into registers, fragment-addressed
    bf16x8 tbh[4], tbl[4];
    auto loadTailB = [&](const unsigned short* PH, const unsigned short* PL,
                         size_t slab, int tc) {
        #pragma unroll
        for (int fg = 0; fg < 4; ++fg) {
            size_t o = slab + (size_t)((tc * 4 + rs) * 64 + fg * 16 + c15) * 8;
            tbh[fg] = *(const bf16x8*)&PH[o];
            tbl[fg] = *(const bf16x8*)&PL[o];
        }
    };

    stageB(WeH, WeL, slabE);
    {
        int tc = (w == 0) ? 16 : (w == 1) ? 17 : (w == 3) ? 15 : -1;
        if (tc >= 0) loadTailB(WeH, WeL, slabE, tc);
    }
    __syncthreads();

    float cr[2][4] = {};                 // cell state: [jjhi][r]
    unsigned tgt = 32;
    unsigned* myc = &cnt[ng * 32];

    auto step = [&](auto NIC, auto NCHC, auto ENCC,
                    const unsigned* __restrict__ hsrc, const unsigned* __restrict__ xsrc,
                    const float (&bj)[2][4], unsigned* __restrict__ hdst)
    {
        constexpr int  NI  = decltype(NIC)::value;    // max chunk-iters per wave
        constexpr int  NCH = decltype(NCHC)::value;   // total chunks
        constexpr bool ENC = decltype(ENCC)::value;

        f32x4 acc[4][4] = {};
        uint4 pend[2][8];

        auto issueA = [&](int i, uint4* dst) {        // 8x16B loads, chunk w+4i
            const int ch = w + 4 * i;
            #pragma unroll
            for (int grp = 0; grp < 4; ++grp) {
                const int r = grp * 16 + srow4;
                const unsigned* src;
                if (ENC && ch >= NCHD)
                    src = &xsrc[(size_t)(n0 + r) * CD + (ch - NCHD) * 32 + sks * 8];
                else
                    src = &hsrc[(size_t)(n0 + r) * HD + ch * 32 + sks * 8];
                dst[grp * 2 + 0] = *(const uint4*)(src);
                dst[grp * 2 + 1] = *(const uint4*)(src + 4);
            }
        };
        auto procA = [&](uint4* pd) {                 // perm-split -> As[w]
            #pragma unroll
            for (int grp = 0; grp < 4; ++grp) {
                const int r = grp * 16 + srow4;
                uint2 h0, l0, h1, l1;
                split4(pd[grp * 2 + 0], h0, l0);
                split4(pd[grp * 2 + 1], h1, l1);
                uint4 hv = {h0.x, h0.y, h1.x, h1.y};
                uint4 lv = {l0.x, l0.y, l1.x, l1.y};
                const int off = aswz(r, sks);
                *(uint4*)((char*)&As[w][0][0] + off) = hv;
                *(uint4*)((char*)&As[w][1][0] + off) = lv;
            }
        };
        auto compute = [&](int ch) {
            bf16x8 bh[4], bl[4];
            if (ch < NBLDS) {
                #pragma unroll
                for (int fg = 0; fg < 4; ++fg) {
                    const int bi = ((ch * 4 + rs) * 64 + fg * 16 + c15) * 8;
                    bh[fg] = *(const bf16x8*)&BhS[bi];
                    bl[fg] = *(const bf16x8*)&BlS[bi];
                }
            } else {
                #pragma unroll
                for (int fg = 0; fg < 4; ++fg) { bh[fg] = tbh[fg]; bl[fg] = tbl[fg]; }
            }
            #pragma unroll
            for (int fm = 0; fm < 4; ++fm) {
                const int off = aswz(fm * 16 + c15, rs);
                bf16x8 ah = *(const bf16x8*)((const char*)&As[w][0][0] + off);
                bf16x8 al = *(const bf16x8*)((const char*)&As[w][1][0] + off);
                #pragma unroll
                for (int fg = 0; fg < 4; ++fg) {
                    acc[fm][fg] = __builtin_amdgcn_mfma_f32_16x16x32_bf16(ah, bh[fg], acc[fm][fg], 0, 0, 0);
                    acc[fm][fg] = __builtin_amdgcn_mfma_f32_16x16x32_bf16(ah, bl[fg], acc[fm][fg], 0, 0, 0);
                    acc[fm][fg] = __builtin_amdgcn_mfma_f32_16x16x32_bf16(al, bh[fg], acc[fm][fg], 0, 0, 0);
                }
            }
        };

        issueA(0, pend[0]);
        if (w + 4 < NCH) issueA(1, pend[1]);
        #pragma unroll
        for (int i = 0; i < NI; ++i) {
            if (w + 4 * i < NCH) {
                procA(pend[i & 1]);
                if (w + 4 * (i + 2) < NCH) issueA(i + 2, pend[i & 1]);
                compute(w + 4 * i);
            }
        }

        // ---- cross-wave reduction: wave w ends owning full acc for fm=w ----
        __syncthreads();
        float* red = (float*)&As[0][0][0];            // 32KB overlay
        #pragma unroll
        for (int pass = 0; pass < 2; ++pass) {
            const int t0 = pass * 2;
            #pragma unroll
            for (int tt = 0; tt < 2; ++tt) {
                const int t = t0 + tt;
                if (w != t) {
                    const int src = w - (w > t ? 1 : 0);
                    float* s = &red[(size_t)(tt * 3 + src) * 1280 + lane * 20];
                    #pragma unroll
                    for (int fg = 0; fg < 4; ++fg)
                        *(f32x4*)&s[fg * 4] = acc[t][fg];
                }
            }
            __syncthreads();
            if (w == t0 || w == t0 + 1) {
                const int tt = w - t0;
                #pragma unroll
                for (int src = 0; src < 3; ++src) {
                    const float* s = &red[(size_t)(tt * 3 + src) * 1280 + lane * 20];
                    #pragma unroll
                    for (int fg = 0; fg < 4; ++fg)
                        acc[w][fg] += *(const f32x4*)&s[fg * 4];
                }
            }
            __syncthreads();
        }

        // ---- epilogue: wave w handles n rows [n0+w*16, +16), j = jbase/+8 ----
        #pragma unroll
        for (int r = 0; r < 4; ++r) {
            float v0 = acc[w][0][r], v1 = acc[w][1][r];
            float v2 = acc[w][2][r], v3 = acc[w][3][r];
            float u0 = __shfl_xor(v0, 8, 64);
            float u1 = __shfl_xor(v1, 8, 64);
            float u2 = __shfl_xor(v2, 8, 64);
            float u3 = __shfl_xor(v3, 8, 64);
            if (p == 0) {
                const int n = n0 + w * 16 + (lane >> 4) * 4 + r;
                {   // jj
                    float gi = v0 + bj[0][0], gf = u0 + bj[0][1];
                    float gg = v1 + bj[0][2], go = u1 + bj[0][3];
                    float cn = sigmf(gf) * cr[0][r] + sigmf(gi) * tanhf(gg);
                    float hn = sigmf(go) * tanhf(cn);
                    cr[0][r] = cn;
                    __hip_atomic_store(&hdst[(size_t)n * HD + jbase], packsplit(hn),
                                       __ATOMIC_RELAXED, __HIP_MEMORY_SCOPE_AGENT);
                }
                {   // jj + 8
                    float gi = v2 + bj[1][0], gf = u2 + bj[1][1];
                    float gg = v3 + bj[1][2], go = u3 + bj[1][3];
                    float cn = sigmf(gf) * cr[1][r] + sigmf(gi) * tanhf(gg);
                    float hn = sigmf(go) * tanhf(cn);
                    cr[1][r] = cn;
                    __hip_atomic_store(&hdst[(size_t)n * HD + jbase + 8], packsplit(hn),
                                       __ATOMIC_RELAXED, __HIP_MEMORY_SCOPE_AGENT);
                }
            }
        }
    };

    auto ngbar = [&]() {
        __syncthreads();   // drains vmcnt: h-stores at agent coherence point
        if (tid == 0) {
            __hip_atomic_fetch_add(myc, 1u, __ATOMIC_RELAXED, __HIP_MEMORY_SCOPE_AGENT);
            while (__hip_atomic_load(myc, __ATOMIC_RELAXED, __HIP_MEMORY_SCOPE_AGENT) < tgt)
                __builtin_amdgcn_s_sleep(1);
        }
        __syncthreads();
        __builtin_amdgcn_fence(__ATOMIC_ACQUIRE, "agent");  // inv stale cached h
        tgt += 32;
    };

    // ---- encoder: 168 steps (even count -> h_enc lands in slot 0) ----
    for (int t = 0; t < TD; ++t) {
        step(icn<5>{}, icn<NCHE>{}, icb<true>{},
             hp + (size_t)(t & 1) * NH, xP + (size_t)t * NB * CD,
             bje, hp + (size_t)((t + 1) & 1) * NH);
        ngbar();
    }

    // ---- swap in decoder weights ----
    stageB(WdH, WdL, slabD);
    if (w == 3) loadTailB(WdH, WdL, slabD, 15);
    __syncthreads();
    #pragma unroll
    for (int jj = 0; jj < 2; ++jj)
        #pragma unroll
        for (int r = 0; r < 4; ++r) cr[jj][r] = 0.f;

    // ---- decoder: 24 steps, outputs land in hs slots ----
    for (int s = 0; s < DSTEPS; ++s) {
        const unsigned* hb = (s == 0) ? hp : hs + (size_t)(s - 1) * NH;
        step(icn<4>{}, icn<NCHD>{}, icb<false>{},
             hb, hb, bjd, hs + (size_t)s * NH);
        ngbar();
    }
}

// ---------------------------------------------------------------------------
// Dense head: out[n][o][t] = sum_k unpack(hs[t][n][k]) * Wd[t][o][k] + bd.
// ---------------------------------------------------------------------------
__global__ __launch_bounds__(256)
void dense_kernel(const unsigned* __restrict__ hsP,
                  const float* __restrict__ Wd,
                  const float* __restrict__ bd,
                  float* __restrict__ out)
{
    const int t  = blockIdx.y;
    const int n0 = blockIdx.x * 64;
    const int tid = threadIdx.x;
    const int to  = tid & 15;
    const int tn  = tid >> 4;

    __shared__ __align__(16) float aT[32 * 68];
    __shared__ __align__(16) float wT[32 * 68];

    float acc[4][4] = {};

    for (int ch = 0; ch < HD / 32; ++ch) {
        const int k0 = ch * 32;
        __syncthreads();
        #pragma unroll
        for (int i = 0; i < 8; ++i) {
            int e  = tid + i * 256;
            int kk = e & 31;
            int nl = e >> 5;
            unsigned v = hsP[((size_t)t * NB + n0 + nl) * HD + k0 + kk];
            aT[kk * 68 + nl] = bf2f((unsigned short)(v >> 16)) + bf2f((unsigned short)(v & 0xffffu));
            wT[kk * 68 + nl] = Wd[((size_t)t * OUTC + nl) * HD + k0 + kk];
        }
        __syncthreads();
        #pragma unroll
        for (int kk = 0; kk < 32; ++kk) {
            float4 a = *reinterpret_cast<const float4*>(&aT[kk * 68 + tn * 4]);
            float4 wv = *reinterpret_cast<const float4*>(&wT[kk * 68 + to * 4]);
            acc[0][0] += a.x * wv.x; acc[0][1] += a.x * wv.y; acc[0][2] += a.x * wv.z; acc[0][3] += a.x * wv.w;
            acc[1][0] += a.y * wv.x; acc[1][1] += a.y * wv.y; acc[1][2] += a.y * wv.z; acc[1][3] += a.y * wv.w;
            acc[2][0] += a.z * wv.x; acc[2][1] += a.z * wv.y; acc[2][2] += a.z * wv.z; acc[2][3] += a.z * wv.w;
            acc[3][0] += a.w * wv.x; acc[3][1] += a.w * wv.y; acc[3][2] += a.w * wv.z; acc[3][3] += a.w * wv.w;
        }
    }

    #pragma unroll
    for (int i = 0; i < 4; ++i)
        #pragma unroll
        for (int jq = 0; jq < 4; ++jq) {
            int n = n0 + tn * 4 + i;
            int o = to * 4 + jq;
            out[((size_t)n * OUTC + o) * DSTEPS + t] = acc[i][jq] + bd[t * OUTC + o];
        }
}

// ---------------------------------------------------------------------------
extern "C" void kernel_launch(void* const* d_in, const int* in_sizes, int n_in,
                              void* d_out, int out_size, void* d_ws, size_t ws_size,
                              hipStream_t stream) {
    const float* x       = (const float*)d_in[0];
    const float* W_ih_e  = (const float*)d_in[1];
    const float* W_hh_e  = (const float*)d_in[2];
    const float* b_e     = (const float*)d_in[3];
    const float* W_hh_d  = (const float*)d_in[4];
    const float* b_d     = (const float*)d_in[5];
    const float* W_dense = (const float*)d_in[6];
    const float* b_dense = (const float*)d_in[7];
    float* out = (float*)d_out;

    const size_t NH = (size_t)NB * HD;   // 262144 elems

    char* pws = (char*)d_ws;
    auto alloc = [&](size_t bytes) { char* q = pws; pws += (bytes + 255) & ~(size_t)255; return q; };
    unsigned short* WeH = (unsigned short*)alloc((size_t)GATES * KWE * 2);
    unsigned short* WeL = (unsigned short*)alloc((size_t)GATES * KWE * 2);
    unsigned short* WdH = (unsigned short*)alloc((size_t)GATES * HD * 2);
    unsigned short* WdL = (unsigned short*)alloc((size_t)GATES * HD * 2);
    unsigned*       xPk = (unsigned*)alloc((size_t)TD * NB * CD * 4);
    unsigned*       hp  = (unsigned*)alloc(2 * NH * 4);
    unsigned*       hs  = (unsigned*)alloc((size_t)DSTEPS * NH * 4);
    unsigned*       cnt = (unsigned*)alloc(8 * 32 * sizeof(unsigned));

    // Prep (every call; deterministic)
    prep_wfrag<<<dim3(32, NCHE), dim3(256), 0, stream>>>(W_hh_e, W_ih_e, WeH, WeL, NCHE);
    prep_wfrag<<<dim3(32, NCHD), dim3(256), 0, stream>>>(W_hh_d, W_hh_d, WdH, WdL, NCHD);
    prep_xPk<<<dim3(NB), dim3(256), 0, stream>>>(x, xPk);

    hipMemsetAsync(hp, 0, NH * 4, stream);                 // slot 0 = zeros
    hipMemsetAsync(cnt, 0, 8 * 32 * sizeof(unsigned), stream);

    lstm_persist<<<dim3(256), dim3(256), 0, stream>>>(
        WeH, WeL, WdH, WdL, xPk, b_e, b_d, hp, hs, cnt);

    dense_kernel<<<dim3(NB / 64, DSTEPS), dim3(256), 0, stream>>>(
        hs, W_dense, b_dense, out);
}

// Round 7
// 3282.251 us; speedup vs baseline: 1.6232x; 1.5270x over previous
//
#include <hip/hip_runtime.h>
#include <math.h>
#include <type_traits>

// Problem constants
#define NB 512     // batch
#define HD 512     // hidden
#define CD 64      // in channels
#define TD 168     // encode length
#define DSTEPS 24  // decoder steps
#define OUTC 64    // out channels
#define GATES 2048 // 4*HD
#define KWE (HD + CD)   // encoder K = 576
#define NCHE 18         // encoder K chunks (32 each)
#define NCHD 16         // decoder K chunks
#define NBLDS 15        // B chunks resident in LDS (rest in regs)

typedef __attribute__((ext_vector_type(8))) short bf16x8;
typedef __attribute__((ext_vector_type(4))) float f32x4;

template<int N>  using icn = std::integral_constant<int, N>;
template<bool B> using icb = std::integral_constant<bool, B>;

__device__ __forceinline__ float sigmf(float x) { return 1.0f / (1.0f + expf(-x)); }
__device__ __forceinline__ float bf2f(unsigned short h) {
    return __uint_as_float(((unsigned)h) << 16);
}
__device__ __forceinline__ unsigned short f2bf(float x) {  // round-to-nearest-even
    unsigned u = __float_as_uint(x);
    return (unsigned short)((u + 0x7fffu + ((u >> 16) & 1u)) >> 16);
}
__device__ __forceinline__ unsigned packsplit(float v) {   // bf16 hi|lo packed
    unsigned short hi = f2bf(v);
    unsigned short lo = f2bf(v - bf2f(hi));
    return ((unsigned)hi << 16) | (unsigned)lo;
}

// A-LDS swizzle: plane is [64 rows][32 bf16]; conflict-free for both the
// 16-rows x 4-ks staging writes and the 16-rows x 4-rs b128 frag reads.
// row-bit0 ^= row-bit2 (stays in-plane), ks ^= row&3.
__device__ __forceinline__ int aswz(int r, int ks) {      // byte offset in 4KB
    return ((r * 64) ^ (((r >> 2) & 1) << 6)) + (((ks ^ r) & 3) * 16);
}

// v_perm split of 4 packed (hi<<16|lo) words -> 2 hi-words + 2 lo-words (x2)
__device__ __forceinline__ void split4(uint4 p, uint2& hi, uint2& lo) {
    hi.x = __builtin_amdgcn_perm(p.y, p.x, 0x07060302u);
    hi.y = __builtin_amdgcn_perm(p.w, p.z, 0x07060302u);
    lo.x = __builtin_amdgcn_perm(p.y, p.x, 0x05040100u);
    lo.y = __builtin_amdgcn_perm(p.w, p.z, 0x05040100u);
}

// ---------------------------------------------------------------------------
// Weight prep: split f32 into bf16 hi/lo planes, permuted + fragment-ready.
// Elem [(ch*4+ks)*64 + gc][m] holds source row gate*HD + jt*16 + jj at
// k = ch*32 + ks*8 + m, with gate=(gc>>3)&3, jj=(gc&7)+8*(gc>>5).
// ---------------------------------------------------------------------------
__global__ __launch_bounds__(256)
void prep_wfrag(const float* __restrict__ Whh, const float* __restrict__ Wih,
                unsigned short* __restrict__ Ph, unsigned short* __restrict__ Pl,
                int nch)
{
    const int jt = blockIdx.x, ch = blockIdx.y;
    const int ks = threadIdx.x >> 6, gc = threadIdx.x & 63;
    const int gate = (gc >> 3) & 3;
    const int jj = (gc & 7) + ((gc >> 5) << 3);
    const int srow = gate * HD + jt * 16 + jj;
    const int k0 = ch * 32 + ks * 8;
    const size_t o = (size_t)jt * (64 * nch * 32) + (size_t)((ch * 4 + ks) * 64 + gc) * 8;
    #pragma unroll
    for (int m = 0; m < 8; ++m) {
        int k = k0 + m;
        float v = (k < HD) ? Whh[(size_t)srow * HD + k] : Wih[(size_t)srow * CD + (k - HD)];
        unsigned short hi = f2bf(v);
        Ph[o + m] = hi;
        Pl[o + m] = f2bf(v - bf2f(hi));
    }
}

// ---------------------------------------------------------------------------
// x prep: (N,C,T) f32 -> packed hi|lo u32 planes xP[t][n][c].
// ---------------------------------------------------------------------------
__global__ __launch_bounds__(256)
void prep_xPk(const float* __restrict__ x, unsigned* __restrict__ Xp)
{
    __shared__ float tile[CD * TD];
    const int n = blockIdx.x;
    for (int e = threadIdx.x; e < CD * TD; e += 256)
        tile[e] = x[(size_t)n * CD * TD + e];
    __syncthreads();
    for (int e = threadIdx.x; e < CD * TD; e += 256) {
        int t = e >> 6, c = e & 63;
        Xp[((size_t)t * NB + n) * CD + c] = packsplit(tile[c * TD + t]);
    }
}

// ---------------------------------------------------------------------------
// Persistent encoder+decoder. 256 blocks x 256 threads (4 waves), 1 block/CU.
// Block (jt = bid>>3, ng = bid&7): tile 64n x 64gc.
// Waves specialize by K-chunk (ch%4==w): each wave computes the FULL 4x4 frag
// tile over its chunks; B-LDS read once per chunk; A staged wave-privately
// (no K-loop barriers, loads 2 chunks ahead). Step end: 2-pass LDS reduction
// into a statically-indexed own[4] (rule #20: no runtime acc indexing!),
// epilogue, packed-u32 h exchange via relaxed agent atomics, per-n-group
// counter barrier + agent acquire fence.
// ---------------------------------------------------------------------------
__global__ __launch_bounds__(256, 1)
void lstm_persist(const unsigned short* __restrict__ WeH, const unsigned short* __restrict__ WeL,
                  const unsigned short* __restrict__ WdH, const unsigned short* __restrict__ WdL,
                  const unsigned* __restrict__ xP,
                  const float* __restrict__ b_e, const float* __restrict__ b_d,
                  unsigned* __restrict__ hp,   // [2][NB*HD] packed
                  unsigned* __restrict__ hs,   // [DSTEPS][NB*HD] packed
                  unsigned* __restrict__ cnt)
{
    __shared__ __align__(16) unsigned short BhS[NBLDS * 2048];  // 61440 B
    __shared__ __align__(16) unsigned short BlS[NBLDS * 2048];  // 61440 B
    __shared__ __align__(16) unsigned short As[4][2][2048];     // 32768 B

    const int tid  = threadIdx.x;
    const int lane = tid & 63;
    const int w    = tid >> 6;          // wave 0..3 (owns chunks ch%4==w, fm=w)
    const int jt   = blockIdx.x >> 3;   // 0..31
    const int ng   = blockIdx.x & 7;    // n-group (== XCD heuristic, perf only)
    const int n0   = ng * 64;

    const int rs    = lane >> 4;        // frag k-slot 0..3
    const int c15   = lane & 15;
    const int p     = (lane >> 3) & 1;
    const int jbase = jt * 16 + (lane & 7);
    const int srow4 = lane >> 2;        // staging sub-row 0..15
    const int sks   = lane & 3;         // staging k-slot 0..3

    const size_t slabE = (size_t)jt * (64 * KWE);
    const size_t slabD = (size_t)jt * (64 * HD);
    const size_t NH    = (size_t)NB * HD;

    // Biases (per-lane, both phases)
    float bje[2][4], bjd[2][4];
    #pragma unroll
    for (int g = 0; g < 4; ++g) {
        bje[0][g] = b_e[g * HD + jbase];
        bje[1][g] = b_e[g * HD + jbase + 8];
        bjd[0][g] = b_d[g * HD + jbase];
        bjd[1][g] = b_d[g * HD + jbase + 8];
    }

    // B-LDS stage (chunks 0..14)
    auto stageB = [&](const unsigned short* PH, const unsigned short* PL, size_t slab) {
        for (int e = tid; e < NBLDS * 256; e += 256) {
            *(bf16x8*)&BhS[(size_t)e * 8] = *(const bf16x8*)&PH[slab + (size_t)e * 8];
            *(bf16x8*)&BlS[(size_t)e * 8] = *(const bf16x8*)&PL[slab + (size_t)e * 8];
        }
    };
    // Tail B chunk (>=15) into registers, fragment-addressed
    bf16x8 tbh[4], tbl[4];
    auto loadTailB = [&](const unsigned short* PH, const unsigned short* PL,
                         size_t slab, int tc) {
        #pragma unroll
        for (int fg = 0; fg < 4; ++fg) {
            size_t o = slab + (size_t)((tc * 4 + rs) * 64 + fg * 16 + c15) * 8;
            tbh[fg] = *(const bf16x8*)&PH[o];
            tbl[fg] = *(const bf16x8*)&PL[o];
        }
    };

    stageB(WeH, WeL, slabE);
    {
        int tc = (w == 0) ? 16 : (w == 1) ? 17 : (w == 3) ? 15 : -1;
        if (tc >= 0) loadTailB(WeH, WeL, slabE, tc);
    }
    __syncthreads();

    float cr[2][4] = {};                 // cell state: [jjhi][r]
    unsigned tgt = 32;
    unsigned* myc = &cnt[ng * 32];

    auto step = [&](auto NIC, auto NCHC, auto ENCC,
                    const unsigned* __restrict__ hsrc, const unsigned* __restrict__ xsrc,
                    const float (&bj)[2][4], unsigned* __restrict__ hdst)
    {
        constexpr int  NI  = decltype(NIC)::value;    // max chunk-iters per wave
        constexpr int  NCH = decltype(NCHC)::value;   // total chunks
        constexpr bool ENC = decltype(ENCC)::value;

        f32x4 acc[4][4] = {};
        uint4 pend[2][8];

        auto issueA = [&](int i, uint4* dst) {        // 8x16B loads, chunk w+4i
            const int ch = w + 4 * i;
            #pragma unroll
            for (int grp = 0; grp < 4; ++grp) {
                const int r = grp * 16 + srow4;
                const unsigned* src;
                if (ENC && ch >= NCHD)
                    src = &xsrc[(size_t)(n0 + r) * CD + (ch - NCHD) * 32 + sks * 8];
                else
                    src = &hsrc[(size_t)(n0 + r) * HD + ch * 32 + sks * 8];
                dst[grp * 2 + 0] = *(const uint4*)(src);
                dst[grp * 2 + 1] = *(const uint4*)(src + 4);
            }
        };
        auto procA = [&](uint4* pd) {                 // perm-split -> As[w]
            #pragma unroll
            for (int grp = 0; grp < 4; ++grp) {
                const int r = grp * 16 + srow4;
                uint2 h0, l0, h1, l1;
                split4(pd[grp * 2 + 0], h0, l0);
                split4(pd[grp * 2 + 1], h1, l1);
                uint4 hv = {h0.x, h0.y, h1.x, h1.y};
                uint4 lv = {l0.x, l0.y, l1.x, l1.y};
                const int off = aswz(r, sks);
                *(uint4*)((char*)&As[w][0][0] + off) = hv;
                *(uint4*)((char*)&As[w][1][0] + off) = lv;
            }
        };
        auto compute = [&](int ch) {
            bf16x8 bh[4], bl[4];
            if (ch < NBLDS) {
                #pragma unroll
                for (int fg = 0; fg < 4; ++fg) {
                    const int bi = ((ch * 4 + rs) * 64 + fg * 16 + c15) * 8;
                    bh[fg] = *(const bf16x8*)&BhS[bi];
                    bl[fg] = *(const bf16x8*)&BlS[bi];
                }
            } else {
                #pragma unroll
                for (int fg = 0; fg < 4; ++fg) { bh[fg] = tbh[fg]; bl[fg] = tbl[fg]; }
            }
            #pragma unroll
            for (int fm = 0; fm < 4; ++fm) {
                const int off = aswz(fm * 16 + c15, rs);
                bf16x8 ah = *(const bf16x8*)((const char*)&As[w][0][0] + off);
                bf16x8 al = *(const bf16x8*)((const char*)&As[w][1][0] + off);
                #pragma unroll
                for (int fg = 0; fg < 4; ++fg) {
                    acc[fm][fg] = __builtin_amdgcn_mfma_f32_16x16x32_bf16(ah, bh[fg], acc[fm][fg], 0, 0, 0);
                    acc[fm][fg] = __builtin_amdgcn_mfma_f32_16x16x32_bf16(ah, bl[fg], acc[fm][fg], 0, 0, 0);
                    acc[fm][fg] = __builtin_amdgcn_mfma_f32_16x16x32_bf16(al, bh[fg], acc[fm][fg], 0, 0, 0);
                }
            }
        };

        issueA(0, pend[0]);
        if (w + 4 < NCH) issueA(1, pend[1]);
        #pragma unroll
        for (int i = 0; i < NI; ++i) {
            if (w + 4 * i < NCH) {
                procA(pend[i & 1]);
                if (w + 4 * (i + 2) < NCH) issueA(i + 2, pend[i & 1]);
                compute(w + 4 * i);
            }
        }

        // ---- cross-wave reduction, ALL-STATIC acc indexing (rule #20) ----
        // Wave w ends owning the full sum for fm=w in own[fg] (registers).
        f32x4 own[4] = {};
        __syncthreads();
        float* red = (float*)&As[0][0][0];            // 32KB overlay
        #pragma unroll
        for (int pass = 0; pass < 2; ++pass) {
            #pragma unroll
            for (int tt = 0; tt < 2; ++tt) {
                const int t = pass * 2 + tt;          // static
                if (w == t) {
                    #pragma unroll
                    for (int fg = 0; fg < 4; ++fg) own[fg] = acc[t][fg];
                } else {
                    const int src = w - (w > t ? 1 : 0);   // runtime: addr only
                    float* s = &red[(size_t)(tt * 3 + src) * 1280 + lane * 20];
                    #pragma unroll
                    for (int fg = 0; fg < 4; ++fg)
                        *(f32x4*)&s[fg * 4] = acc[t][fg];
                }
            }
            __syncthreads();
            if ((w >> 1) == pass) {
                const int tt = w & 1;                 // runtime: addr only
                #pragma unroll
                for (int src = 0; src < 3; ++src) {
                    const float* s = &red[(size_t)(tt * 3 + src) * 1280 + lane * 20];
                    #pragma unroll
                    for (int fg = 0; fg < 4; ++fg)
                        own[fg] += *(const f32x4*)&s[fg * 4];
                }
            }
            __syncthreads();
        }

        // ---- epilogue: wave w handles n rows [n0+w*16, +16), j = jbase/+8 ----
        #pragma unroll
        for (int r = 0; r < 4; ++r) {
            float v0 = own[0][r], v1 = own[1][r];
            float v2 = own[2][r], v3 = own[3][r];
            float u0 = __shfl_xor(v0, 8, 64);
            float u1 = __shfl_xor(v1, 8, 64);
            float u2 = __shfl_xor(v2, 8, 64);
            float u3 = __shfl_xor(v3, 8, 64);
            if (p == 0) {
                const int n = n0 + w * 16 + (lane >> 4) * 4 + r;
                {   // jj
                    float gi = v0 + bj[0][0], gf = u0 + bj[0][1];
                    float gg = v1 + bj[0][2], go = u1 + bj[0][3];
                    float cn = sigmf(gf) * cr[0][r] + sigmf(gi) * tanhf(gg);
                    float hn = sigmf(go) * tanhf(cn);
                    cr[0][r] = cn;
                    __hip_atomic_store(&hdst[(size_t)n * HD + jbase], packsplit(hn),
                                       __ATOMIC_RELAXED, __HIP_MEMORY_SCOPE_AGENT);
                }
                {   // jj + 8
                    float gi = v2 + bj[1][0], gf = u2 + bj[1][1];
                    float gg = v3 + bj[1][2], go = u3 + bj[1][3];
                    float cn = sigmf(gf) * cr[1][r] + sigmf(gi) * tanhf(gg);
                    float hn = sigmf(go) * tanhf(cn);
                    cr[1][r] = cn;
                    __hip_atomic_store(&hdst[(size_t)n * HD + jbase + 8], packsplit(hn),
                                       __ATOMIC_RELAXED, __HIP_MEMORY_SCOPE_AGENT);
                }
            }
        }
    };

    auto ngbar = [&]() {
        __syncthreads();   // drains vmcnt: h-stores at agent coherence point
        if (tid == 0) {
            __hip_atomic_fetch_add(myc, 1u, __ATOMIC_RELAXED, __HIP_MEMORY_SCOPE_AGENT);
            while (__hip_atomic_load(myc, __ATOMIC_RELAXED, __HIP_MEMORY_SCOPE_AGENT) < tgt)
                __builtin_amdgcn_s_sleep(1);
        }
        __syncthreads();
        __builtin_amdgcn_fence(__ATOMIC_ACQUIRE, "agent");  // inv stale cached h
        tgt += 32;
    };

    // ---- encoder: 168 steps (even count -> h_enc lands in slot 0) ----
    for (int t = 0; t < TD; ++t) {
        step(icn<5>{}, icn<NCHE>{}, icb<true>{},
             hp + (size_t)(t & 1) * NH, xP + (size_t)t * NB * CD,
             bje, hp + (size_t)((t + 1) & 1) * NH);
        ngbar();
    }

    // ---- swap in decoder weights ----
    stageB(WdH, WdL, slabD);
    if (w == 3) loadTailB(WdH, WdL, slabD, 15);
    __syncthreads();
    #pragma unroll
    for (int jj = 0; jj < 2; ++jj)
        #pragma unroll
        for (int r = 0; r < 4; ++r) cr[jj][r] = 0.f;

    // ---- decoder: 24 steps, outputs land in hs slots ----
    for (int s = 0; s < DSTEPS; ++s) {
        const unsigned* hb = (s == 0) ? hp : hs + (size_t)(s - 1) * NH;
        step(icn<4>{}, icn<NCHD>{}, icb<false>{},
             hb, hb, bjd, hs + (size_t)s * NH);
        ngbar();
    }
}

// ---------------------------------------------------------------------------
// Dense head: out[n][o][t] = sum_k unpack(hs[t][n][k]) * Wd[t][o][k] + bd.
// ---------------------------------------------------------------------------
__global__ __launch_bounds__(256)
void dense_kernel(const unsigned* __restrict__ hsP,
                  const float* __restrict__ Wd,
                  const float* __restrict__ bd,
                  float* __restrict__ out)
{
    const int t  = blockIdx.y;
    const int n0 = blockIdx.x * 64;
    const int tid = threadIdx.x;
    const int to  = tid & 15;
    const int tn  = tid >> 4;

    __shared__ __align__(16) float aT[32 * 68];
    __shared__ __align__(16) float wT[32 * 68];

    float acc[4][4] = {};

    for (int ch = 0; ch < HD / 32; ++ch) {
        const int k0 = ch * 32;
        __syncthreads();
        #pragma unroll
        for (int i = 0; i < 8; ++i) {
            int e  = tid + i * 256;
            int kk = e & 31;
            int nl = e >> 5;
            unsigned v = hsP[((size_t)t * NB + n0 + nl) * HD + k0 + kk];
            aT[kk * 68 + nl] = bf2f((unsigned short)(v >> 16)) + bf2f((unsigned short)(v & 0xffffu));
            wT[kk * 68 + nl] = Wd[((size_t)t * OUTC + nl) * HD + k0 + kk];
        }
        __syncthreads();
        #pragma unroll
        for (int kk = 0; kk < 32; ++kk) {
            float4 a = *reinterpret_cast<const float4*>(&aT[kk * 68 + tn * 4]);
            float4 wv = *reinterpret_cast<const float4*>(&wT[kk * 68 + to * 4]);
            acc[0][0] += a.x * wv.x; acc[0][1] += a.x * wv.y; acc[0][2] += a.x * wv.z; acc[0][3] += a.x * wv.w;
            acc[1][0] += a.y * wv.x; acc[1][1] += a.y * wv.y; acc[1][2] += a.y * wv.z; acc[1][3] += a.y * wv.w;
            acc[2][0] += a.z * wv.x; acc[2][1] += a.z * wv.y; acc[2][2] += a.z * wv.z; acc[2][3] += a.z * wv.w;
            acc[3][0] += a.w * wv.x; acc[3][1] += a.w * wv.y; acc[3][2] += a.w * wv.z; acc[3][3] += a.w * wv.w;
        }
    }

    #pragma unroll
    for (int i = 0; i < 4; ++i)
        #pragma unroll
        for (int jq = 0; jq < 4; ++jq) {
            int n = n0 + tn * 4 + i;
            int o = to * 4 + jq;
            out[((size_t)n * OUTC + o) * DSTEPS + t] = acc[i][jq] + bd[t * OUTC + o];
        }
}

// ---------------------------------------------------------------------------
extern "C" void kernel_launch(void* const* d_in, const int* in_sizes, int n_in,
                              void* d_out, int out_size, void* d_ws, size_t ws_size,
                              hipStream_t stream) {
    const float* x       = (const float*)d_in[0];
    const float* W_ih_e  = (const float*)d_in[1];
    const float* W_hh_e  = (const float*)d_in[2];
    const float* b_e     = (const float*)d_in[3];
    const float* W_hh_d  = (const float*)d_in[4];
    const float* b_d     = (const float*)d_in[5];
    const float* W_dense = (const float*)d_in[6];
    const float* b_dense = (const float*)d_in[7];
    float* out = (float*)d_out;

    const size_t NH = (size_t)NB * HD;   // 262144 elems

    char* pws = (char*)d_ws;
    auto alloc = [&](size_t bytes) { char* q = pws; pws += (bytes + 255) & ~(size_t)255; return q; };
    unsigned short* WeH = (unsigned short*)alloc((size_t)GATES * KWE * 2);
    unsigned short* WeL = (unsigned short*)alloc((size_t)GATES * KWE * 2);
    unsigned short* WdH = (unsigned short*)alloc((size_t)GATES * HD * 2);
    unsigned short* WdL = (unsigned short*)alloc((size_t)GATES * HD * 2);
    unsigned*       xPk = (unsigned*)alloc((size_t)TD * NB * CD * 4);
    unsigned*       hp  = (unsigned*)alloc(2 * NH * 4);
    unsigned*       hs  = (unsigned*)alloc((size_t)DSTEPS * NH * 4);
    unsigned*       cnt = (unsigned*)alloc(8 * 32 * sizeof(unsigned));

    // Prep (every call; deterministic)
    prep_wfrag<<<dim3(32, NCHE), dim3(256), 0, stream>>>(W_hh_e, W_ih_e, WeH, WeL, NCHE);
    prep_wfrag<<<dim3(32, NCHD), dim3(256), 0, stream>>>(W_hh_d, W_hh_d, WdH, WdL, NCHD);
    prep_xPk<<<dim3(NB), dim3(256), 0, stream>>>(x, xPk);

    hipMemsetAsync(hp, 0, NH * 4, stream);                 // slot 0 = zeros
    hipMemsetAsync(cnt, 0, 8 * 32 * sizeof(unsigned), stream);

    lstm_persist<<<dim3(256), dim3(256), 0, stream>>>(
        WeH, WeL, WdH, WdL, xPk, b_e, b_d, hp, hs, cnt);

    dense_kernel<<<dim3(NB / 64, DSTEPS), dim3(256), 0, stream>>>(
        hs, W_dense, b_dense, out);
}

// Round 9
// 3276.994 us; speedup vs baseline: 1.6258x; 1.0016x over previous
//
#include <hip/hip_runtime.h>
#include <math.h>
#include <type_traits>

// Problem constants
#define NB 512     // batch
#define HD 512     // hidden
#define CD 64      // in channels
#define TD 168     // encode length
#define DSTEPS 24  // decoder steps
#define OUTC 64    // out channels
#define GATES 2048 // 4*HD
#define KWE (HD + CD)   // encoder K = 576
#define NCHE 18         // encoder K chunks (32 each)
#define NCHD 16         // decoder K chunks
#define NBLDS 17        // B chunks in LDS (encoder chunk 17 in regs on q=1 waves)

typedef short bf16x8 __attribute__((ext_vector_type(8)));
typedef float f32x4 __attribute__((ext_vector_type(4)));
typedef unsigned u32x4 __attribute__((ext_vector_type(4)));   // native vec for asm "v"

template<bool B> using icb = std::integral_constant<bool, B>;

__device__ __forceinline__ float sigmf(float x) { return 1.0f / (1.0f + expf(-x)); }
__device__ __forceinline__ float bf2f(unsigned short h) {
    return __uint_as_float(((unsigned)h) << 16);
}
__device__ __forceinline__ unsigned short f2bf(float x) {  // round-to-nearest-even
    unsigned u = __float_as_uint(x);
    return (unsigned short)((u + 0x7fffu + ((u >> 16) & 1u)) >> 16);
}
__device__ __forceinline__ unsigned packsplit(float v) {   // bf16 hi|lo packed
    unsigned short hi = f2bf(v);
    unsigned short lo = f2bf(v - bf2f(hi));
    return ((unsigned)hi << 16) | (unsigned)lo;
}

// Build hi/lo bf16x8 fragments from 8 packed (hi<<16|lo) words via v_perm.
__device__ __forceinline__ void mkfrag(u32x4 a, u32x4 b, bf16x8& hi, bf16x8& lo) {
    u32x4 h, l;
    h.x = __builtin_amdgcn_perm(a.y, a.x, 0x07060302u);
    h.y = __builtin_amdgcn_perm(a.w, a.z, 0x07060302u);
    h.z = __builtin_amdgcn_perm(b.y, b.x, 0x07060302u);
    h.w = __builtin_amdgcn_perm(b.w, b.z, 0x07060302u);
    l.x = __builtin_amdgcn_perm(a.y, a.x, 0x05040100u);
    l.y = __builtin_amdgcn_perm(a.w, a.z, 0x05040100u);
    l.z = __builtin_amdgcn_perm(b.y, b.x, 0x05040100u);
    l.w = __builtin_amdgcn_perm(b.w, b.z, 0x05040100u);
    hi = *(bf16x8*)&h;
    lo = *(bf16x8*)&l;
}

// ---------------------------------------------------------------------------
// Weight prep (unchanged): bf16 hi/lo planes, permuted + fragment-ready.
// Elem [(ch*4+ks)*64 + gc][m] holds source row gate*HD + jt*16 + jj at
// k = ch*32 + ks*8 + m, with gate=(gc>>3)&3, jj=(gc&7)+8*(gc>>5).
// ---------------------------------------------------------------------------
__global__ __launch_bounds__(256)
void prep_wfrag(const float* __restrict__ Whh, const float* __restrict__ Wih,
                unsigned short* __restrict__ Ph, unsigned short* __restrict__ Pl,
                int nch)
{
    const int jt = blockIdx.x, ch = blockIdx.y;
    const int ks = threadIdx.x >> 6, gc = threadIdx.x & 63;
    const int gate = (gc >> 3) & 3;
    const int jj = (gc & 7) + ((gc >> 5) << 3);
    const int srow = gate * HD + jt * 16 + jj;
    const int k0 = ch * 32 + ks * 8;
    const size_t o = (size_t)jt * (64 * nch * 32) + (size_t)((ch * 4 + ks) * 64 + gc) * 8;
    #pragma unroll
    for (int m = 0; m < 8; ++m) {
        int k = k0 + m;
        float v = (k < HD) ? Whh[(size_t)srow * HD + k] : Wih[(size_t)srow * CD + (k - HD)];
        unsigned short hi = f2bf(v);
        Ph[o + m] = hi;
        Pl[o + m] = f2bf(v - bf2f(hi));
    }
}

// ---------------------------------------------------------------------------
// x prep: (N,C,T) f32 -> packed u32, TILED: xT[t][ng][ct][64][16],
// ct = c>>4 (4 tiles of 16 channels), row = n&63, col = c&15.
// ---------------------------------------------------------------------------
__global__ __launch_bounds__(256)
void prep_xT(const float* __restrict__ x, unsigned* __restrict__ Xt)
{
    __shared__ float tile[CD * TD];
    const int n = blockIdx.x;
    for (int e = threadIdx.x; e < CD * TD; e += 256)
        tile[e] = x[(size_t)n * CD * TD + e];
    __syncthreads();
    for (int e = threadIdx.x; e < CD * TD; e += 256) {
        int t = e >> 6, c = e & 63;
        size_t o = ((size_t)(t * 8 + (n >> 6)) * 4 + (c >> 4)) * 1024 + (n & 63) * 16 + (c & 15);
        Xt[o] = packsplit(tile[c * TD + t]);
    }
}

// ---------------------------------------------------------------------------
// Persistent encoder+decoder. 256 blocks x 256 threads (4 waves), 1 block/CU.
// Block (jt = bid>>3, ng = bid&7): tile 64n x 64gc.
// Wave w = (p2 = w>>1: fm-pair) x (q = w&1: chunk parity). A fragments load
// DIRECTLY from tiled global h (no A-LDS); all h loads of a step issue at
// once; B in LDS; partner reduction via 20KB LDS; h written via LDS tile +
// one coalesced sc0/sc1 dwordx4 store per thread; x prefetched across the
// barrier with a counted vmcnt(4).
// ---------------------------------------------------------------------------
__global__ __launch_bounds__(256, 1)
void lstm_persist(const unsigned short* __restrict__ WeH, const unsigned short* __restrict__ WeL,
                  const unsigned short* __restrict__ WdH, const unsigned short* __restrict__ WdL,
                  const unsigned* __restrict__ xT,
                  const float* __restrict__ b_e, const float* __restrict__ b_d,
                  unsigned* __restrict__ hp,   // [2][NB*HD] packed, tiled
                  unsigned* __restrict__ hs,   // [DSTEPS][NB*HD] packed, tiled
                  unsigned* __restrict__ cnt)
{
    __shared__ __align__(16) unsigned short BhS[NBLDS * 2048];  // 69632 B
    __shared__ __align__(16) unsigned short BlS[NBLDS * 2048];  // 69632 B
    __shared__ __align__(16) float red[4 * 1280];               // 20480 B

    const int tid  = threadIdx.x;
    const int lane = tid & 63;
    const int w    = tid >> 6;          // wave 0..3
    const int p2   = w >> 1;            // fm-pair (rows p2*32..+31)
    const int q    = w & 1;             // chunk parity
    const int jt   = blockIdx.x >> 3;   // 0..31
    const int ng   = blockIdx.x & 7;    // n-group (== XCD heuristic, perf only)

    const int rs    = lane >> 4;        // frag k-slot 0..3
    const int c15   = lane & 15;
    const int pl    = (lane >> 3) & 1;
    const int jbase = jt * 16 + (lane & 7);
    // per-lane u32 offset within a 1024-u32 tile for fragment rows:
    const int rowcol0 = (p2 * 32 + c15) * 16 + (rs & 1) * 8;        // fmL=0
    const int rowcol1 = (p2 * 32 + 16 + c15) * 16 + (rs & 1) * 8;   // fmL=1
    const int tsub    = rs >> 1;        // which of the chunk's 2 tiles

    const size_t slabE = (size_t)jt * (64 * KWE);
    const size_t slabD = (size_t)jt * (64 * HD);
    const size_t NH    = (size_t)NB * HD;   // u32 elems per h buffer

    // Biases
    float bje[2][4], bjd[2][4];
    #pragma unroll
    for (int g = 0; g < 4; ++g) {
        bje[0][g] = b_e[g * HD + jbase];
        bje[1][g] = b_e[g * HD + jbase + 8];
        bjd[0][g] = b_d[g * HD + jbase];
        bjd[1][g] = b_d[g * HD + jbase + 8];
    }

    auto stageB = [&](const unsigned short* PH, const unsigned short* PL,
                      size_t slab, int nchunks) {
        for (int e = tid; e < nchunks * 256; e += 256) {
            *(bf16x8*)&BhS[(size_t)e * 8] = *(const bf16x8*)&PH[slab + (size_t)e * 8];
            *(bf16x8*)&BlS[(size_t)e * 8] = *(const bf16x8*)&PL[slab + (size_t)e * 8];
        }
    };
    // Encoder tail B chunk (17) in regs on q==1 waves.
    bf16x8 tbh[4], tbl[4];
    if (q == 1) {
        #pragma unroll
        for (int fg = 0; fg < 4; ++fg) {
            size_t o = slabE + (size_t)((17 * 4 + rs) * 64 + fg * 16 + c15) * 8;
            tbh[fg] = *(const bf16x8*)&WeH[o];
            tbl[fg] = *(const bf16x8*)&WeL[o];
        }
    }
    stageB(WeH, WeL, slabE, NBLDS);

    // x prefetch regs (chunk 16 for q=0, 17 for q=1)
    u32x4 xpend[4];
    auto loadX = [&](int t) {
        const unsigned* xb = xT + (size_t)((t * 8 + ng) * 4) * 1024;
        const unsigned* s0 = xb + (q * 2 + tsub) * 1024 + rowcol0;
        const unsigned* s1 = xb + (q * 2 + tsub) * 1024 + rowcol1;
        xpend[0] = *(const u32x4*)s0; xpend[1] = *(const u32x4*)(s0 + 4);
        xpend[2] = *(const u32x4*)s1; xpend[3] = *(const u32x4*)(s1 + 4);
    };
    loadX(0);
    __syncthreads();

    float cr[2][4] = {};                 // cell state [jjhi][r]
    unsigned tgt = 32;
    unsigned* myc = &cnt[ng * 32];

    auto step = [&](auto HASXC,
                    const unsigned* __restrict__ hb,    // ng-offset tiled h src
                    const float (&bj)[2][4],
                    unsigned* __restrict__ hdst)        // full tiled base
    {
        constexpr bool HASX = decltype(HASXC)::value;
        f32x4 acc[2][4] = {};            // [fmL][fg]
        u32x4 pend[8][4];

        // Issue ALL h loads for this step (coalesced 1KB windows per instr).
        #pragma unroll
        for (int i = 0; i < 8; ++i) {
            const int ch = q + 2 * i;
            const unsigned* s0 = hb + (2 * ch + tsub) * 1024 + rowcol0;
            const unsigned* s1 = hb + (2 * ch + tsub) * 1024 + rowcol1;
            pend[i][0] = *(const u32x4*)s0; pend[i][1] = *(const u32x4*)(s0 + 4);
            pend[i][2] = *(const u32x4*)s1; pend[i][3] = *(const u32x4*)(s1 + 4);
        }

        // K-loop: 8 h chunks (+1 x chunk), no intra-loop barriers.
        #pragma unroll
        for (int i = 0; i < 8; ++i) {
            const int ch = q + 2 * i;
            bf16x8 bh[4], bl[4];
            #pragma unroll
            for (int fg = 0; fg < 4; ++fg) {
                const int bi = ((ch * 4 + rs) * 64 + fg * 16 + c15) * 8;
                bh[fg] = *(const bf16x8*)&BhS[bi];
                bl[fg] = *(const bf16x8*)&BlS[bi];
            }
            bf16x8 ah0, al0, ah1, al1;
            mkfrag(pend[i][0], pend[i][1], ah0, al0);
            mkfrag(pend[i][2], pend[i][3], ah1, al1);
            #pragma unroll
            for (int fg = 0; fg < 4; ++fg) {
                acc[0][fg] = __builtin_amdgcn_mfma_f32_16x16x32_bf16(ah0, bh[fg], acc[0][fg], 0, 0, 0);
                acc[0][fg] = __builtin_amdgcn_mfma_f32_16x16x32_bf16(ah0, bl[fg], acc[0][fg], 0, 0, 0);
                acc[0][fg] = __builtin_amdgcn_mfma_f32_16x16x32_bf16(al0, bh[fg], acc[0][fg], 0, 0, 0);
                acc[1][fg] = __builtin_amdgcn_mfma_f32_16x16x32_bf16(ah1, bh[fg], acc[1][fg], 0, 0, 0);
                acc[1][fg] = __builtin_amdgcn_mfma_f32_16x16x32_bf16(ah1, bl[fg], acc[1][fg], 0, 0, 0);
                acc[1][fg] = __builtin_amdgcn_mfma_f32_16x16x32_bf16(al1, bh[fg], acc[1][fg], 0, 0, 0);
            }
        }
        if constexpr (HASX) {            // x chunk (16 on q=0, 17 on q=1)
            bf16x8 bh[4], bl[4];
            if (q == 0) {
                #pragma unroll
                for (int fg = 0; fg < 4; ++fg) {
                    const int bi = ((16 * 4 + rs) * 64 + fg * 16 + c15) * 8;
                    bh[fg] = *(const bf16x8*)&BhS[bi];
                    bl[fg] = *(const bf16x8*)&BlS[bi];
                }
            } else {
                #pragma unroll
                for (int fg = 0; fg < 4; ++fg) { bh[fg] = tbh[fg]; bl[fg] = tbl[fg]; }
            }
            bf16x8 ah0, al0, ah1, al1;
            mkfrag(xpend[0], xpend[1], ah0, al0);
            mkfrag(xpend[2], xpend[3], ah1, al1);
            #pragma unroll
            for (int fg = 0; fg < 4; ++fg) {
                acc[0][fg] = __builtin_amdgcn_mfma_f32_16x16x32_bf16(ah0, bh[fg], acc[0][fg], 0, 0, 0);
                acc[0][fg] = __builtin_amdgcn_mfma_f32_16x16x32_bf16(ah0, bl[fg], acc[0][fg], 0, 0, 0);
                acc[0][fg] = __builtin_amdgcn_mfma_f32_16x16x32_bf16(al0, bh[fg], acc[0][fg], 0, 0, 0);
                acc[1][fg] = __builtin_amdgcn_mfma_f32_16x16x32_bf16(ah1, bh[fg], acc[1][fg], 0, 0, 0);
                acc[1][fg] = __builtin_amdgcn_mfma_f32_16x16x32_bf16(ah1, bl[fg], acc[1][fg], 0, 0, 0);
                acc[1][fg] = __builtin_amdgcn_mfma_f32_16x16x32_bf16(al1, bh[fg], acc[1][fg], 0, 0, 0);
            }
        }

        // Partner reduction: wave w keeps fm = w (static acc indexing only).
        f32x4 keep[4], give[4];
        if (q == 0) {
            #pragma unroll
            for (int fg = 0; fg < 4; ++fg) { keep[fg] = acc[0][fg]; give[fg] = acc[1][fg]; }
        } else {
            #pragma unroll
            for (int fg = 0; fg < 4; ++fg) { keep[fg] = acc[1][fg]; give[fg] = acc[0][fg]; }
        }
        float* myslot = &red[w * 1280 + lane * 20];
        #pragma unroll
        for (int fg = 0; fg < 4; ++fg) *(f32x4*)&myslot[fg * 4] = give[fg];
        __syncthreads();
        const float* ps = &red[(w ^ 1) * 1280 + lane * 20];
        #pragma unroll
        for (int fg = 0; fg < 4; ++fg) keep[fg] += *(const f32x4*)&ps[fg * 4];
        __syncthreads();                 // red free -> otile overlay safe

        // Epilogue -> LDS out-tile (4KB), then coalesced sc1 store.
        unsigned* otile = (unsigned*)red;
        #pragma unroll
        for (int r = 0; r < 4; ++r) {
            float v0 = keep[0][r], v1 = keep[1][r];
            float v2 = keep[2][r], v3 = keep[3][r];
            float u0 = __shfl_xor(v0, 8, 64);
            float u1 = __shfl_xor(v1, 8, 64);
            float u2 = __shfl_xor(v2, 8, 64);
            float u3 = __shfl_xor(v3, 8, 64);
            if (pl == 0) {
                const int row = w * 16 + (lane >> 4) * 4 + r;
                {
                    float gi = v0 + bj[0][0], gf = u0 + bj[0][1];
                    float gg = v1 + bj[0][2], go = u1 + bj[0][3];
                    float cn = sigmf(gf) * cr[0][r] + sigmf(gi) * tanhf(gg);
                    float hn = sigmf(go) * tanhf(cn);
                    cr[0][r] = cn;
                    otile[row * 16 + (lane & 7)] = packsplit(hn);
                }
                {
                    float gi = v2 + bj[1][0], gf = u2 + bj[1][1];
                    float gg = v3 + bj[1][2], go = u3 + bj[1][3];
                    float cn = sigmf(gf) * cr[1][r] + sigmf(gi) * tanhf(gg);
                    float hn = sigmf(go) * tanhf(cn);
                    cr[1][r] = cn;
                    otile[row * 16 + (lane & 7) + 8] = packsplit(hn);
                }
            }
        }
        __syncthreads();
        u32x4 hv = *(const u32x4*)&otile[tid * 4];
        unsigned* dst = hdst + (size_t)(ng * 32 + jt) * 1024 + tid * 4;
        asm volatile("global_store_dwordx4 %0, %1, off sc0 sc1"
                     :: "v"(dst), "v"(hv) : "memory");
    };

    auto ngbar = [&](bool xinflight) {
        // Drain only the h store (x prefetch stays in flight when present).
        if (xinflight) asm volatile("s_waitcnt vmcnt(4) lgkmcnt(0)" ::: "memory");
        else           asm volatile("s_waitcnt vmcnt(0) lgkmcnt(0)" ::: "memory");
        asm volatile("s_barrier" ::: "memory");
        if (tid == 0) {
            __hip_atomic_fetch_add(myc, 1u, __ATOMIC_RELAXED, __HIP_MEMORY_SCOPE_AGENT);
            while (__hip_atomic_load(myc, __ATOMIC_RELAXED, __HIP_MEMORY_SCOPE_AGENT) < tgt)
                __builtin_amdgcn_s_sleep(1);
        }
        asm volatile("s_barrier" ::: "memory");
        __builtin_amdgcn_fence(__ATOMIC_ACQUIRE, "agent");  // inv stale cached h
        tgt += 32;
    };

    // ---- encoder: 168 steps (even count -> h_enc lands in slot 0) ----
    for (int t = 0; t < TD; ++t) {
        step(icb<true>{},
             hp + (size_t)(t & 1) * NH + ng * 32768,
             bje,
             hp + (size_t)((t + 1) & 1) * NH);
        bool more = (t + 1 < TD);
        if (more) loadX(t + 1);          // overlaps the barrier wait
        ngbar(more);
    }

    // ---- swap in decoder weights ----
    stageB(WdH, WdL, slabD, NCHD);
    __syncthreads();
    #pragma unroll
    for (int jj = 0; jj < 2; ++jj)
        #pragma unroll
        for (int r = 0; r < 4; ++r) cr[jj][r] = 0.f;

    // ---- decoder: 24 steps, outputs land in hs slots ----
    for (int s = 0; s < DSTEPS; ++s) {
        const unsigned* hb = ((s == 0) ? hp : hs + (size_t)(s - 1) * NH) + ng * 32768;
        step(icb<false>{}, hb, bjd, hs + (size_t)s * NH);
        ngbar(false);
    }
}

// ---------------------------------------------------------------------------
// Dense head over TILED hs: out[n][o][t] = sum_k unpack(hs) * Wd + bd.
// ---------------------------------------------------------------------------
__global__ __launch_bounds__(256)
void dense_kernel(const unsigned* __restrict__ hsP,
                  const float* __restrict__ Wd,
                  const float* __restrict__ bd,
                  float* __restrict__ out)
{
    const int t  = blockIdx.y;
    const int gx = blockIdx.x;          // n-group (n0 = gx*64)
    const int tid = threadIdx.x;
    const int to  = tid & 15;
    const int tn  = tid >> 4;

    __shared__ __align__(16) float aT[32 * 68];
    __shared__ __align__(16) float wT[32 * 68];

    float acc[4][4] = {};

    for (int ch = 0; ch < HD / 32; ++ch) {
        const int k0 = ch * 32;
        __syncthreads();
        #pragma unroll
        for (int i = 0; i < 8; ++i) {
            int e  = tid + i * 256;
            int kk = e & 31;
            int nl = e >> 5;
            int k  = k0 + kk;
            unsigned v = hsP[(size_t)t * (NB * HD)
                             + (size_t)(gx * 32 + (k >> 4)) * 1024 + nl * 16 + (k & 15)];
            aT[kk * 68 + nl] = bf2f((unsigned short)(v >> 16)) + bf2f((unsigned short)(v & 0xffffu));
            wT[kk * 68 + nl] = Wd[((size_t)t * OUTC + nl) * HD + k];
        }
        __syncthreads();
        #pragma unroll
        for (int kk = 0; kk < 32; ++kk) {
            float4 a = *reinterpret_cast<const float4*>(&aT[kk * 68 + tn * 4]);
            float4 wv = *reinterpret_cast<const float4*>(&wT[kk * 68 + to * 4]);
            acc[0][0] += a.x * wv.x; acc[0][1] += a.x * wv.y; acc[0][2] += a.x * wv.z; acc[0][3] += a.x * wv.w;
            acc[1][0] += a.y * wv.x; acc[1][1] += a.y * wv.y; acc[1][2] += a.y * wv.z; acc[1][3] += a.y * wv.w;
            acc[2][0] += a.z * wv.x; acc[2][1] += a.z * wv.y; acc[2][2] += a.z * wv.z; acc[2][3] += a.z * wv.w;
            acc[3][0] += a.w * wv.x; acc[3][1] += a.w * wv.y; acc[3][2] += a.w * wv.z; acc[3][3] += a.w * wv.w;
        }
    }

    #pragma unroll
    for (int i = 0; i < 4; ++i)
        #pragma unroll
        for (int jq = 0; jq < 4; ++jq) {
            int n = gx * 64 + tn * 4 + i;
            int o = to * 4 + jq;
            out[((size_t)n * OUTC + o) * DSTEPS + t] = acc[i][jq] + bd[t * OUTC + o];
        }
}

// ---------------------------------------------------------------------------
extern "C" void kernel_launch(void* const* d_in, const int* in_sizes, int n_in,
                              void* d_out, int out_size, void* d_ws, size_t ws_size,
                              hipStream_t stream) {
    const float* x       = (const float*)d_in[0];
    const float* W_ih_e  = (const float*)d_in[1];
    const float* W_hh_e  = (const float*)d_in[2];
    const float* b_e     = (const float*)d_in[3];
    const float* W_hh_d  = (const float*)d_in[4];
    const float* b_d     = (const float*)d_in[5];
    const float* W_dense = (const float*)d_in[6];
    const float* b_dense = (const float*)d_in[7];
    float* out = (float*)d_out;

    const size_t NH = (size_t)NB * HD;   // 262144 u32 elems

    char* pws = (char*)d_ws;
    auto alloc = [&](size_t bytes) { char* q = pws; pws += (bytes + 255) & ~(size_t)255; return q; };
    unsigned short* WeH = (unsigned short*)alloc((size_t)GATES * KWE * 2);
    unsigned short* WeL = (unsigned short*)alloc((size_t)GATES * KWE * 2);
    unsigned short* WdH = (unsigned short*)alloc((size_t)GATES * HD * 2);
    unsigned short* WdL = (unsigned short*)alloc((size_t)GATES * HD * 2);
    unsigned*       xTl = (unsigned*)alloc((size_t)TD * NB * CD * 4);
    unsigned*       hp  = (unsigned*)alloc(2 * NH * 4);
    unsigned*       hs  = (unsigned*)alloc((size_t)DSTEPS * NH * 4);
    unsigned*       cnt = (unsigned*)alloc(8 * 32 * sizeof(unsigned));

    // Prep (every call; deterministic)
    prep_wfrag<<<dim3(32, NCHE), dim3(256), 0, stream>>>(W_hh_e, W_ih_e, WeH, WeL, NCHE);
    prep_wfrag<<<dim3(32, NCHD), dim3(256), 0, stream>>>(W_hh_d, W_hh_d, WdH, WdL, NCHD);
    prep_xT<<<dim3(NB), dim3(256), 0, stream>>>(x, xTl);

    (void)hipMemsetAsync(hp, 0, NH * 4, stream);                 // slot 0 = zeros
    (void)hipMemsetAsync(cnt, 0, 8 * 32 * sizeof(unsigned), stream);

    lstm_persist<<<dim3(256), dim3(256), 0, stream>>>(
        WeH, WeL, WdH, WdL, xTl, b_e, b_d, hp, hs, cnt);

    dense_kernel<<<dim3(NB / 64, DSTEPS), dim3(256), 0, stream>>>(
        hs, W_dense, b_dense, out);
}